// Round 1
// baseline (395.504 us; speedup 1.0000x reference)
//
#include <hip/hip_runtime.h>
#include <hip/hip_bf16.h>

// TT-linear: out(8192x4096) = x(8192x4096) @ W(4096x4096),
//   W[(m1*64+m2),(n1*64+n2)] = sum_r g1[0,m1,n1,r] * g2[r,m2,n2,0]
// Plan: (1) cvt x -> bf16, (2) build W^T (n-major) in bf16, (3) bf16 MFMA GEMM.

#define TOKENS 8192
#define KDIM 4096
#define NDIM 4096

typedef __attribute__((ext_vector_type(8))) __bf16 bf16x8;
typedef __attribute__((ext_vector_type(4))) float f32x4;
typedef __attribute__((ext_vector_type(8))) unsigned short u16x8;

typedef __attribute__((address_space(1))) unsigned int as1_uint;
typedef __attribute__((address_space(3))) unsigned int as3_uint;

// global_load_lds width=16: LDS dest = (wave-uniform base) + lane*16, global src per-lane.
#define GLOAD_LDS16(gp, lp) \
  __builtin_amdgcn_global_load_lds((as1_uint*)(void*)(gp), (as3_uint*)(lp), 16, 0, 0)

__device__ inline unsigned short f2bf(float f) {
  __hip_bfloat16 h = __float2bfloat16(f);
  return __builtin_bit_cast(unsigned short, h);
}

// ---------------- Kernel 1: x (fp32) -> bf16, 8 elems/thread ----------------
__global__ __launch_bounds__(256) void cvt_x_kernel(const float* __restrict__ x,
                                                    unsigned short* __restrict__ xb) {
  size_t i = (size_t)blockIdx.x * 256 + threadIdx.x;  // grid sized exactly: no bounds check
  const float4* p = reinterpret_cast<const float4*>(x) + i * 2;
  float4 v0 = p[0];
  float4 v1 = p[1];
  u16x8 u;
  u[0] = f2bf(v0.x); u[1] = f2bf(v0.y); u[2] = f2bf(v0.z); u[3] = f2bf(v0.w);
  u[4] = f2bf(v1.x); u[5] = f2bf(v1.y); u[6] = f2bf(v1.z); u[7] = f2bf(v1.w);
  reinterpret_cast<u16x8*>(xb)[i] = u;
}

// ---------------- Kernel 2: build Wt[n][k] (bf16), one block per n ----------------
// g1: (1,64,64,16)  a[m1][n1][r] at m1*1024 + n1*16 + r
// g2: (16,64,64,1)  b[r][m2][n2] at r*4096 + m2*64 + n2
// Wt[n][k] = sum_r a[k>>6][n>>6][r] * b[r][k&63][n&63]
__global__ __launch_bounds__(256) void build_wt_kernel(const float* __restrict__ g1,
                                                       const float* __restrict__ g2,
                                                       unsigned short* __restrict__ wt) {
  __shared__ float a_s[64 * 16];  // [m1][r] for fixed n1
  __shared__ float b_s[16 * 64];  // [r][m2] for fixed n2
  const int n = blockIdx.x;
  const int n1 = n >> 6, n2 = n & 63;
  const int t = threadIdx.x;

  for (int e = t; e < 1024; e += 256) {
    int m1 = e >> 4, r = e & 15;
    a_s[e] = g1[m1 * 1024 + n1 * 16 + r];
  }
  for (int e = t; e < 1024; e += 256) {
    int r = e >> 6, m2 = e & 63;
    b_s[e] = g2[r * 4096 + m2 * 64 + n2];
  }
  __syncthreads();

  unsigned short loc[16];
  const int kbase = t * 16;  // 256 threads * 16 = 4096 k
#pragma unroll
  for (int kk = 0; kk < 16; ++kk) {
    int k = kbase + kk;
    int m1 = k >> 6, m2 = k & 63;
    float acc = 0.f;
#pragma unroll
    for (int r = 0; r < 16; ++r) acc += a_s[m1 * 16 + r] * b_s[r * 64 + m2];
    loc[kk] = f2bf(acc);
  }
  u16x8* dst = reinterpret_cast<u16x8*>(wt + (size_t)n * KDIM + kbase);
  dst[0] = *reinterpret_cast<u16x8*>(&loc[0]);
  dst[1] = *reinterpret_cast<u16x8*>(&loc[8]);
}

// ---------------- Kernel 3: bf16 GEMM, 128x128 tile, BK=32, 4 waves (2x2) ----------------
// out[m][n] = sum_k Xb[m][k] * Wt[n][k]   (Wt is n-major so both LDS tiles are [128][32])
__global__ __launch_bounds__(256, 3) void gemm_kernel(const unsigned short* __restrict__ Xb,
                                                      const unsigned short* __restrict__ Wt,
                                                      float* __restrict__ out) {
  __shared__ __align__(16) unsigned short As[128 * 32];  // [m_local][k_local]
  __shared__ __align__(16) unsigned short Bs[128 * 32];  // [n_local][k_local]

  // XCD-aware bijective swizzle (nwg = 2048, divisible by 8)
  const int nwg = gridDim.x;
  const int cpx = nwg >> 3;
  const int bid = blockIdx.x;
  const int wg = (bid & 7) * cpx + (bid >> 3);
  const int NBN = NDIM / 128;  // 32
  const int bm = wg / NBN, bn = wg % NBN;
  const int m0 = bm << 7, n0 = bn << 7;

  const int t = threadIdx.x;
  const int lane = t & 63;
  const int wave = t >> 6;        // 0..3
  const int wm = wave >> 1;       // wave row (0..1), owns 64 output rows
  const int wn = wave & 1;        // wave col (0..1), owns 64 output cols

  // staging: thread t loads 16B at row (t>>2), col8 (t&3)*8; iter1 adds 64 rows
  const int row_a = t >> 2;
  const int c8 = (t & 3) << 3;
  const unsigned short* Ag = Xb + (size_t)(m0 + row_a) * KDIM + c8;
  const unsigned short* Bg = Wt + (size_t)(n0 + row_a) * KDIM + c8;
  char* AsB = (char*)As + (size_t)wave * 1024;  // wave-uniform LDS base
  char* BsB = (char*)Bs + (size_t)wave * 1024;

  f32x4 acc[4][4];
#pragma unroll
  for (int i = 0; i < 4; ++i)
#pragma unroll
    for (int j = 0; j < 4; ++j) acc[i][j] = (f32x4){0.f, 0.f, 0.f, 0.f};

  const int lrow = lane & 15;
  const int lk = (lane >> 4) << 3;

  for (int k0 = 0; k0 < KDIM; k0 += 32) {
    __syncthreads();  // previous compute done before overwriting LDS
    GLOAD_LDS16(Ag + k0, AsB);
    GLOAD_LDS16(Ag + k0 + (size_t)64 * KDIM, AsB + 4096);
    GLOAD_LDS16(Bg + k0, BsB);
    GLOAD_LDS16(Bg + k0 + (size_t)64 * KDIM, BsB + 4096);
    __syncthreads();  // emits s_waitcnt vmcnt(0) before s_barrier -> staged data visible

    bf16x8 af[4], bf[4];
#pragma unroll
    for (int i = 0; i < 4; ++i)
      af[i] = *reinterpret_cast<const bf16x8*>(&As[(wm * 64 + i * 16 + lrow) * 32 + lk]);
#pragma unroll
    for (int j = 0; j < 4; ++j)
      bf[j] = *reinterpret_cast<const bf16x8*>(&Bs[(wn * 64 + j * 16 + lrow) * 32 + lk]);
#pragma unroll
    for (int i = 0; i < 4; ++i)
#pragma unroll
      for (int j = 0; j < 4; ++j)
        acc[i][j] = __builtin_amdgcn_mfma_f32_16x16x32_bf16(af[i], bf[j], acc[i][j], 0, 0, 0);
  }

  // epilogue: C/D layout col = lane&15, row = (lane>>4)*4 + q  [m89-verified]
  const int crow = (lane >> 4) << 2;
  const int ccol = lane & 15;
#pragma unroll
  for (int i = 0; i < 4; ++i) {
#pragma unroll
    for (int j = 0; j < 4; ++j) {
      size_t base = (size_t)(m0 + wm * 64 + i * 16 + crow) * NDIM + (n0 + wn * 64 + j * 16 + ccol);
#pragma unroll
      for (int q = 0; q < 4; ++q) out[base + (size_t)q * NDIM] = acc[i][j][q];
    }
  }
}

extern "C" void kernel_launch(void* const* d_in, const int* in_sizes, int n_in,
                              void* d_out, int out_size, void* d_ws, size_t ws_size,
                              hipStream_t stream) {
  const float* x = (const float*)d_in[0];
  const float* g1 = (const float*)d_in[1];
  const float* g2 = (const float*)d_in[2];
  float* out = (float*)d_out;

  // workspace layout: Wt (4096*4096 bf16 = 33.5MB) then Xb (8192*4096 bf16 = 67MB)
  unsigned short* Wt = (unsigned short*)d_ws;
  unsigned short* Xb = (unsigned short*)d_ws + (size_t)KDIM * NDIM;

  cvt_x_kernel<<<(TOKENS * KDIM / 8) / 256, 256, 0, stream>>>(x, Xb);
  build_wt_kernel<<<NDIM, 256, 0, stream>>>(g1, g2, Wt);
  gemm_kernel<<<(TOKENS / 128) * (NDIM / 128), 256, 0, stream>>>(Xb, Wt, out);
}

// Round 2
// 287.303 us; speedup vs baseline: 1.3766x; 1.3766x over previous
//
#include <hip/hip_runtime.h>
#include <hip/hip_bf16.h>

// TT-linear: out(8192x4096) = x @ W, W from TT cores g1,g2.
// (1) cvt x->bf16, (2) build W^T bf16, (3) 256x256 8-phase bf16 MFMA GEMM (m201 template).

#define TOKENS 8192
#define KDIM 4096
#define NDIM 4096

typedef __attribute__((ext_vector_type(8))) __bf16 bf16x8;
typedef __attribute__((ext_vector_type(4))) float f32x4;
typedef __attribute__((ext_vector_type(8))) unsigned short u16x8;

typedef __attribute__((address_space(1))) unsigned int as1_uint;
typedef __attribute__((address_space(3))) unsigned int as3_uint;

#define GLOAD_LDS16(gp, lp) \
  __builtin_amdgcn_global_load_lds((as1_uint*)(void*)(gp), (as3_uint*)(void*)(lp), 16, 0, 0)

#define BAR() asm volatile("s_barrier" ::: "memory")
#define LGKM0() asm volatile("s_waitcnt lgkmcnt(0)" ::: "memory")
#define VMCNT4() asm volatile("s_waitcnt vmcnt(4)" ::: "memory")

__device__ inline unsigned short f2bf(float f) {
  __hip_bfloat16 h = __float2bfloat16(f);
  return __builtin_bit_cast(unsigned short, h);
}

// ---------------- Kernel 1: x (fp32) -> bf16 ----------------
__global__ __launch_bounds__(256) void cvt_x_kernel(const float* __restrict__ x,
                                                    unsigned short* __restrict__ xb) {
  size_t i = (size_t)blockIdx.x * 256 + threadIdx.x;
  const float4* p = reinterpret_cast<const float4*>(x) + i * 2;
  float4 v0 = p[0];
  float4 v1 = p[1];
  u16x8 u;
  u[0] = f2bf(v0.x); u[1] = f2bf(v0.y); u[2] = f2bf(v0.z); u[3] = f2bf(v0.w);
  u[4] = f2bf(v1.x); u[5] = f2bf(v1.y); u[6] = f2bf(v1.z); u[7] = f2bf(v1.w);
  reinterpret_cast<u16x8*>(xb)[i] = u;
}

// ---------------- Kernel 2: build Wt[n][k] (bf16) ----------------
__global__ __launch_bounds__(256) void build_wt_kernel(const float* __restrict__ g1,
                                                       const float* __restrict__ g2,
                                                       unsigned short* __restrict__ wt) {
  __shared__ float a_s[64 * 16];  // [m1][r] for fixed n1
  __shared__ float b_s[16 * 64];  // [r][m2] for fixed n2
  const int n = blockIdx.x;
  const int n1 = n >> 6, n2 = n & 63;
  const int t = threadIdx.x;

  for (int e = t; e < 1024; e += 256) {
    int m1 = e >> 4, r = e & 15;
    a_s[e] = g1[m1 * 1024 + n1 * 16 + r];
  }
  for (int e = t; e < 1024; e += 256) {
    int r = e >> 6, m2 = e & 63;
    b_s[e] = g2[r * 4096 + m2 * 64 + n2];
  }
  __syncthreads();

  unsigned short loc[16];
  const int kbase = t * 16;
#pragma unroll
  for (int kk = 0; kk < 16; ++kk) {
    int k = kbase + kk;
    int m1 = k >> 6, m2 = k & 63;
    float acc = 0.f;
#pragma unroll
    for (int r = 0; r < 16; ++r) acc += a_s[m1 * 16 + r] * b_s[r * 64 + m2];
    loc[kk] = f2bf(acc);
  }
  u16x8* dst = reinterpret_cast<u16x8*>(wt + (size_t)n * KDIM + kbase);
  dst[0] = *reinterpret_cast<u16x8*>(&loc[0]);
  dst[1] = *reinterpret_cast<u16x8*>(&loc[8]);
}

// ---------------- Kernel 3: 256x256 8-phase bf16 GEMM ----------------
// out[m][n] = sum_k Xb[m][k] * Wt[n][k]; both LDS tiles [256 rows][64 k] bf16,
// stored as 2 halves of [128][64] with XOR-chunk swizzle c16' = c16 ^ (row&7).
// LDS: buf b at b*65536; A at +0 (2x16KB halves), B at +32768.
__global__ __launch_bounds__(512, 2) void gemm_kernel(const unsigned short* __restrict__ Xb,
                                                      const unsigned short* __restrict__ Wt,
                                                      float* __restrict__ out) {
  __shared__ __align__(16) char lds[131072];

  const int t = threadIdx.x;
  const int lane = t & 63;
  const int wave = t >> 6;   // 0..7
  const int wm = wave >> 2;  // 0..1 : owns 128 output rows
  const int wn = wave & 3;   // 0..3 : owns 64 output cols

  // XCD-bijective swizzle: 512 blocks, 512 % 8 == 0
  const int bid = blockIdx.x;
  const int wg = (bid & 7) * 64 + (bid >> 3);
  const int bm = wg >> 4, bn = wg & 15;  // NBM=32, NBN=16
  const int m0 = bm << 8, n0 = bn << 8;

  // ---- staging geometry (rule #21: linear LDS dest, inverse-swizzled global src) ----
  const int srow = (wave << 3) + (lane >> 3);         // 0..63 within a 64-row slab
  const int c16f = (lane & 7) ^ (lane >> 3);          // fetched 16B-chunk
  const unsigned short* aSrc = Xb + (size_t)(m0 + srow) * KDIM + c16f * 8;
  const unsigned short* bSrc = Wt + (size_t)(n0 + srow) * KDIM + c16f * 8;
  const int ldsW = wave << 10;  // wave-uniform 1KB slot

#define STAGE_A(tt, h) do { \
    const unsigned short* _s = aSrc + (size_t)((h) * 128) * KDIM + (tt) * 64; \
    char* _d = lds + ((tt) & 1) * 65536 + (h) * 16384 + ldsW; \
    GLOAD_LDS16(_s, _d); \
    GLOAD_LDS16(_s + (size_t)64 * KDIM, _d + 8192); \
  } while (0)

#define STAGE_B(tt, h) do { \
    const unsigned short* _s = bSrc + (size_t)((h) * 128) * KDIM + (tt) * 64; \
    char* _d = lds + ((tt) & 1) * 65536 + 32768 + (h) * 16384 + ldsW; \
    GLOAD_LDS16(_s, _d); \
    GLOAD_LDS16(_s + (size_t)64 * KDIM, _d + 8192); \
  } while (0)

  // ---- fragment-read geometry (swizzled) ----
  const int aRowB = (wm * 128 + (lane & 15)) * 128;           // byte row base in A region
  const int bRowB = 32768 + (wn * 64 + (lane & 15)) * 128;    // byte row base in B region
  const int cOff0 = (((lane >> 4)) ^ (lane & 7)) << 4;        // kk=0 chunk byte offset
  const int cOff1 = ((4 + (lane >> 4)) ^ (lane & 7)) << 4;    // kk=1

#define RA(i, co) (*(const bf16x8*)(lds + bufB + aRowB + (i) * 2048 + (co)))
#define RB(j, co) (*(const bf16x8*)(lds + bufB + bRowB + (j) * 2048 + (co)))
#define MF(i, j, A, B) acc[i][j] = __builtin_amdgcn_mfma_f32_16x16x32_bf16((A), (B), acc[i][j], 0, 0, 0)

  f32x4 acc[8][4];
#pragma unroll
  for (int i = 0; i < 8; ++i)
#pragma unroll
    for (int j = 0; j < 4; ++j) acc[i][j] = (f32x4){0.f, 0.f, 0.f, 0.f};

  // ---- prologue: tile0 (A+B), tile1 (A); keep tile1-A in flight ----
  STAGE_A(0, 0); STAGE_A(0, 1); STAGE_B(0, 0); STAGE_B(0, 1);
  STAGE_A(1, 0); STAGE_A(1, 1);
  VMCNT4();  // tile0's 8 loads retired; tile1-A (4) in flight
  BAR();

#pragma unroll 1
  for (int tt = 0; tt < 64; ++tt) {
    const int bufB = (tt & 1) * 65536;
    const int t1 = (tt + 1) & 63;  // wraps at tail: harmless dummy stages
    const int t2 = (tt + 2) & 63;

    // ---- phase 1: A kk0 m0-3 + B kk0 ; stage B-h0(t+1) ; MFMA i0-3 kk0 ----
    bf16x8 pa0 = RA(0, cOff0), pa1 = RA(1, cOff0), pa2 = RA(2, cOff0), pa3 = RA(3, cOff0);
    bf16x8 pb0 = RB(0, cOff0), pb1 = RB(1, cOff0), pb2 = RB(2, cOff0), pb3 = RB(3, cOff0);
    STAGE_B(t1, 0);
    BAR(); LGKM0();
    __builtin_amdgcn_s_setprio(1);
    MF(0, 0, pa0, pb0); MF(0, 1, pa0, pb1); MF(0, 2, pa0, pb2); MF(0, 3, pa0, pb3);
    MF(1, 0, pa1, pb0); MF(1, 1, pa1, pb1); MF(1, 2, pa1, pb2); MF(1, 3, pa1, pb3);
    MF(2, 0, pa2, pb0); MF(2, 1, pa2, pb1); MF(2, 2, pa2, pb2); MF(2, 3, pa2, pb3);
    MF(3, 0, pa3, pb0); MF(3, 1, pa3, pb1); MF(3, 2, pa3, pb2); MF(3, 3, pa3, pb3);
    __builtin_amdgcn_s_setprio(0);
    BAR();

    // ---- phase 2: A kk0 m4-7 + A kk1 m0-3 ; stage B-h1(t+1) ; MFMA i4-7 kk0 ----
    bf16x8 pa4 = RA(4, cOff0), pa5 = RA(5, cOff0), pa6 = RA(6, cOff0), pa7 = RA(7, cOff0);
    bf16x8 qa0 = RA(0, cOff1), qa1 = RA(1, cOff1), qa2 = RA(2, cOff1), qa3 = RA(3, cOff1);
    STAGE_B(t1, 1);
    BAR(); LGKM0();
    __builtin_amdgcn_s_setprio(1);
    MF(4, 0, pa4, pb0); MF(4, 1, pa4, pb1); MF(4, 2, pa4, pb2); MF(4, 3, pa4, pb3);
    MF(5, 0, pa5, pb0); MF(5, 1, pa5, pb1); MF(5, 2, pa5, pb2); MF(5, 3, pa5, pb3);
    MF(6, 0, pa6, pb0); MF(6, 1, pa6, pb1); MF(6, 2, pa6, pb2); MF(6, 3, pa6, pb3);
    MF(7, 0, pa7, pb0); MF(7, 1, pa7, pb1); MF(7, 2, pa7, pb2); MF(7, 3, pa7, pb3);
    __builtin_amdgcn_s_setprio(0);
    BAR();

    // ---- phase 3: A kk1 m4-7 + B kk1 ; stage A-h0(t+2) ; MFMA i0-3 kk1 ----
    bf16x8 qa4 = RA(4, cOff1), qa5 = RA(5, cOff1), qa6 = RA(6, cOff1), qa7 = RA(7, cOff1);
    bf16x8 qb0 = RB(0, cOff1), qb1 = RB(1, cOff1), qb2 = RB(2, cOff1), qb3 = RB(3, cOff1);
    STAGE_A(t2, 0);
    BAR(); LGKM0();
    __builtin_amdgcn_s_setprio(1);
    MF(0, 0, qa0, qb0); MF(0, 1, qa0, qb1); MF(0, 2, qa0, qb2); MF(0, 3, qa0, qb3);
    MF(1, 0, qa1, qb0); MF(1, 1, qa1, qb1); MF(1, 2, qa1, qb2); MF(1, 3, qa1, qb3);
    MF(2, 0, qa2, qb0); MF(2, 1, qa2, qb1); MF(2, 2, qa2, qb2); MF(2, 3, qa2, qb3);
    MF(3, 0, qa3, qb0); MF(3, 1, qa3, qb1); MF(3, 2, qa3, qb2); MF(3, 3, qa3, qb3);
    __builtin_amdgcn_s_setprio(0);
    BAR();

    // ---- phase 4: stage A-h1(t+2) ; vmcnt(4) -> tile t+1 resident ; MFMA i4-7 kk1 ----
    STAGE_A(t2, 1);
    VMCNT4();
    BAR();
    __builtin_amdgcn_s_setprio(1);
    MF(4, 0, qa4, qb0); MF(4, 1, qa4, qb1); MF(4, 2, qa4, qb2); MF(4, 3, qa4, qb3);
    MF(5, 0, qa5, qb0); MF(5, 1, qa5, qb1); MF(5, 2, qa5, qb2); MF(5, 3, qa5, qb3);
    MF(6, 0, qa6, qb0); MF(6, 1, qa6, qb1); MF(6, 2, qa6, qb2); MF(6, 3, qa6, qb3);
    MF(7, 0, qa7, qb0); MF(7, 1, qa7, qb1); MF(7, 2, qa7, qb2); MF(7, 3, qa7, qb3);
    __builtin_amdgcn_s_setprio(0);
    BAR();
  }

  // ---- epilogue: C/D layout col = lane&15, row = (lane>>4)*4 + q ----
  const int crow = (lane >> 4) << 2;
  const int ccol = lane & 15;
#pragma unroll
  for (int i = 0; i < 8; ++i) {
#pragma unroll
    for (int j = 0; j < 4; ++j) {
      size_t base = (size_t)(m0 + wm * 128 + i * 16 + crow) * NDIM + (n0 + wn * 64 + j * 16 + ccol);
#pragma unroll
      for (int q = 0; q < 4; ++q) out[base + (size_t)q * NDIM] = acc[i][j][q];
    }
  }
}

extern "C" void kernel_launch(void* const* d_in, const int* in_sizes, int n_in,
                              void* d_out, int out_size, void* d_ws, size_t ws_size,
                              hipStream_t stream) {
  const float* x = (const float*)d_in[0];
  const float* g1 = (const float*)d_in[1];
  const float* g2 = (const float*)d_in[2];
  float* out = (float*)d_out;

  unsigned short* Wt = (unsigned short*)d_ws;
  unsigned short* Xb = (unsigned short*)d_ws + (size_t)KDIM * NDIM;

  cvt_x_kernel<<<(TOKENS * KDIM / 8) / 256, 256, 0, stream>>>(x, Xb);
  build_wt_kernel<<<NDIM, 256, 0, stream>>>(g1, g2, Wt);
  gemm_kernel<<<(TOKENS / 256) * (NDIM / 256), 512, 0, stream>>>(Xb, Wt, out);
}